// Round 1
// baseline (3747.828 us; speedup 1.0000x reference)
//
#include <hip/hip_runtime.h>
#include <cmath>

#define D_MODEL 1024
#define N_HEADS 16
#define D_HEAD  64
#define BATCH   2
#define SEQ     2048
#define M_TOT   (BATCH*SEQ)   // 4096

// ---------------------------------------------------------------------------
// GEMM: C[M,N] = A[M,K] @ W[K,N] + bias[N]     (M=4096, N=K=1024, fp32)
// 64x64 block tile, 256 threads, 4x4 micro-tile per thread, K-tile 16.
// HEAD_LAYOUT=true writes C into [B][H][S][64] (head-split) layout.
// ---------------------------------------------------------------------------
template<bool HEAD_LAYOUT>
__global__ __launch_bounds__(256)
void gemm_bias_kernel(const float* __restrict__ A, const float* __restrict__ W,
                      const float* __restrict__ bias, float* __restrict__ out)
{
    __shared__ float As[16][68];   // [k][m] transposed A tile (pad 68: float4-aligned rows)
    __shared__ float Bs[16][68];   // [k][n]

    const int t  = threadIdx.x;
    const int tx = t & 15;         // col group (4 cols each)
    const int ty = t >> 4;         // row group (4 rows each)
    const int m0 = blockIdx.y * 64;
    const int n0 = blockIdx.x * 64;

    float acc[4][4];
#pragma unroll
    for (int i = 0; i < 4; ++i)
#pragma unroll
        for (int j = 0; j < 4; ++j) acc[i][j] = 0.f;

    for (int kt = 0; kt < D_MODEL; kt += 16) {
        __syncthreads();
        // --- load A tile (64 rows x 16 k), store transposed to As[k][m]
        {
            const int r  = t >> 2;          // 0..63
            const int c4 = (t & 3) * 4;     // 0,4,8,12
            const float4 av = *(const float4*)&A[(size_t)(m0 + r) * D_MODEL + kt + c4];
            As[c4 + 0][r] = av.x;
            As[c4 + 1][r] = av.y;
            As[c4 + 2][r] = av.z;
            As[c4 + 3][r] = av.w;
        }
        // --- load B tile (16 k x 64 n)
        {
            const int kr = t >> 4;          // 0..15
            const int c4 = (t & 15) * 4;    // 0..60
            const float4 bv4 = *(const float4*)&W[(size_t)(kt + kr) * D_MODEL + n0 + c4];
            *(float4*)&Bs[kr][c4] = bv4;
        }
        __syncthreads();

#pragma unroll
        for (int k = 0; k < 16; ++k) {
            float a[4], b[4];
#pragma unroll
            for (int i = 0; i < 4; ++i) a[i] = As[k][ty * 4 + i];
#pragma unroll
            for (int j = 0; j < 4; ++j) b[j] = Bs[k][tx * 4 + j];
#pragma unroll
            for (int i = 0; i < 4; ++i)
#pragma unroll
                for (int j = 0; j < 4; ++j) acc[i][j] += a[i] * b[j];
        }
    }

#pragma unroll
    for (int i = 0; i < 4; ++i) {
        const int m = m0 + ty * 4 + i;
#pragma unroll
        for (int j = 0; j < 4; ++j) {
            const int n = n0 + tx * 4 + j;
            const float c = acc[i][j] + bias[n];
            if (HEAD_LAYOUT) {
                const int b  = m >> 11;          // m / SEQ
                const int s  = m & (SEQ - 1);
                const int h  = n >> 6;           // n / 64
                const int dh = n & 63;
                out[(((size_t)(b * N_HEADS + h)) * SEQ + s) * D_HEAD + dh] = c;
            } else {
                out[(size_t)m * D_MODEL + n] = c;
            }
        }
    }
}

// ---------------------------------------------------------------------------
// Flash attention (fp32). One block = 64 query rows of one (b,h).
// 256 threads: thread (r = t>>2, q = t&3) owns row r; quarter q covers
// 16 keys (scores) / 16 output dims (PV). Online softmax, 4-lane shfl reduce.
// K and V share one LDS buffer (loaded sequentially per tile).
// ---------------------------------------------------------------------------
__global__ __launch_bounds__(256)
void flash_attn_kernel(const float* __restrict__ Q, const float* __restrict__ K,
                       const float* __restrict__ V, float* __restrict__ AO)
{
    __shared__ float Qs[64][65];
    __shared__ float KVs[64][65];
    __shared__ float Ps[64][65];

    const int t  = threadIdx.x;
    const int r  = t >> 2;    // 0..63
    const int q  = t & 3;     // 0..3
    const int qt = blockIdx.x;          // query tile 0..31
    const int bh = blockIdx.y;          // 0..31 = b*H + h
    const size_t base = (size_t)bh * SEQ * D_HEAD;
    const float scale = 0.125f;         // 1/sqrt(64)

    // load Q tile (rows qt*64..qt*64+63)
#pragma unroll
    for (int u = 0; u < 4; ++u) {
        const float4 v = *(const float4*)&Q[base + (size_t)(qt * 64 + r) * D_HEAD + q * 16 + u * 4];
        Qs[r][q * 16 + u * 4 + 0] = v.x;
        Qs[r][q * 16 + u * 4 + 1] = v.y;
        Qs[r][q * 16 + u * 4 + 2] = v.z;
        Qs[r][q * 16 + u * 4 + 3] = v.w;
    }

    float m_r = -INFINITY, l_r = 0.f;
    float o[16];
#pragma unroll
    for (int j = 0; j < 16; ++j) o[j] = 0.f;

    for (int kt = 0; kt < SEQ / 64; ++kt) {
        __syncthreads();   // previous PV done before overwriting KVs
        // load K tile
#pragma unroll
        for (int u = 0; u < 4; ++u) {
            const float4 v = *(const float4*)&K[base + (size_t)(kt * 64 + r) * D_HEAD + q * 16 + u * 4];
            KVs[r][q * 16 + u * 4 + 0] = v.x;
            KVs[r][q * 16 + u * 4 + 1] = v.y;
            KVs[r][q * 16 + u * 4 + 2] = v.z;
            KVs[r][q * 16 + u * 4 + 3] = v.w;
        }
        __syncthreads();

        // scores for my row r, keys q*16..q*16+15
        float sv[16];
#pragma unroll
        for (int i = 0; i < 16; ++i) {
            const int kc = q * 16 + i;
            float s = 0.f;
#pragma unroll
            for (int d = 0; d < 64; ++d) s += Qs[r][d] * KVs[kc][d];
            sv[i] = s * scale;
        }

        // online softmax
        float mloc = sv[0];
#pragma unroll
        for (int i = 1; i < 16; ++i) mloc = fmaxf(mloc, sv[i]);
        mloc = fmaxf(mloc, __shfl_xor(mloc, 1, 64));
        mloc = fmaxf(mloc, __shfl_xor(mloc, 2, 64));
        const float m_new = fmaxf(m_r, mloc);
        const float alpha = __expf(m_r - m_new);
        l_r *= alpha;
#pragma unroll
        for (int j = 0; j < 16; ++j) o[j] *= alpha;
        float psum = 0.f;
#pragma unroll
        for (int i = 0; i < 16; ++i) {
            const float p = __expf(sv[i] - m_new);
            Ps[r][q * 16 + i] = p;
            psum += p;
        }
        psum += __shfl_xor(psum, 1, 64);
        psum += __shfl_xor(psum, 2, 64);
        l_r += psum;
        m_r = m_new;
        __syncthreads();   // Ps visible; all score reads of KVs done

        // load V tile into same buffer
#pragma unroll
        for (int u = 0; u < 4; ++u) {
            const float4 v = *(const float4*)&V[base + (size_t)(kt * 64 + r) * D_HEAD + q * 16 + u * 4];
            KVs[r][q * 16 + u * 4 + 0] = v.x;
            KVs[r][q * 16 + u * 4 + 1] = v.y;
            KVs[r][q * 16 + u * 4 + 2] = v.z;
            KVs[r][q * 16 + u * 4 + 3] = v.w;
        }
        __syncthreads();

        // PV accumulate: o[j] += sum_k Ps[r][k] * V[k][q*16+j]
#pragma unroll
        for (int k = 0; k < 64; ++k) {
            const float p = Ps[r][k];
#pragma unroll
            for (int j = 0; j < 16; ++j) o[j] += p * KVs[k][q * 16 + j];
        }
    }

    const float inv = 1.f / l_r;
    const int b = bh >> 4;
    const int h = bh & 15;
    const size_t row = (size_t)b * SEQ + qt * 64 + r;
#pragma unroll
    for (int j = 0; j < 16; ++j)
        AO[row * D_MODEL + h * D_HEAD + q * 16 + j] = o[j] * inv;
}

// ---------------------------------------------------------------------------
extern "C" void kernel_launch(void* const* d_in, const int* in_sizes, int n_in,
                              void* d_out, int out_size, void* d_ws, size_t ws_size,
                              hipStream_t stream)
{
    const float* x  = (const float*)d_in[0];
    const float* Wq = (const float*)d_in[1];
    const float* bq = (const float*)d_in[2];
    const float* Wk = (const float*)d_in[3];
    const float* bk = (const float*)d_in[4];
    const float* Wv = (const float*)d_in[5];
    const float* bv = (const float*)d_in[6];
    const float* Wo = (const float*)d_in[7];
    const float* bo = (const float*)d_in[8];
    float* out = (float*)d_out;

    float* ws = (float*)d_ws;
    const size_t NELT = (size_t)M_TOT * D_MODEL;   // 4M floats
    float* Qb = ws;
    float* Kb = ws + NELT;
    float* Vb = ws + 2 * NELT;
    float* AO = ws + 3 * NELT;

    const dim3 gg(D_MODEL / 64, M_TOT / 64);   // 16 x 64
    gemm_bias_kernel<true ><<<gg, 256, 0, stream>>>(x,  Wq, bq, Qb);
    gemm_bias_kernel<true ><<<gg, 256, 0, stream>>>(x,  Wk, bk, Kb);
    gemm_bias_kernel<true ><<<gg, 256, 0, stream>>>(x,  Wv, bv, Vb);
    flash_attn_kernel<<<dim3(SEQ / 64, BATCH * N_HEADS), 256, 0, stream>>>(Qb, Kb, Vb, AO);
    gemm_bias_kernel<false><<<gg, 256, 0, stream>>>(AO, Wo, bo, out);
}

// Round 3
// 773.796 us; speedup vs baseline: 4.8434x; 4.8434x over previous
//
#include <hip/hip_runtime.h>
#include <hip/hip_bf16.h>
#include <cmath>

#define D_MODEL 1024
#define N_HEADS 16
#define D_HEAD  64
#define BATCH   2
#define SEQ     2048
#define M_TOT   (BATCH*SEQ)   // 4096

typedef __attribute__((ext_vector_type(8))) short short8;   // 8 bf16 (4 VGPRs)
typedef __attribute__((ext_vector_type(4))) float f32x4;

static __device__ __forceinline__ ushort f2bf(float f) {
    __hip_bfloat16 h = __float2bfloat16(f);   // RNE
    return *reinterpret_cast<ushort*>(&h);
}

// ---------------------------------------------------------------------------
// GEMM: C[M,N] = A[M,K] @ W[K,N] + bias[N]   (M=4096, N=K=1024, fp32 compute)
// MODE 0: fp32 row-major out.
// MODE 1: bf16 out, head layout [B][H][S][64], value scaled by `scale`.
// MODE 2: bf16 out, transposed head layout [B][H][64][S].
// ---------------------------------------------------------------------------
template<int MODE>
__global__ __launch_bounds__(256)
void gemm_bias_kernel(const float* __restrict__ A, const float* __restrict__ W,
                      const float* __restrict__ bias, void* __restrict__ outp,
                      float scale)
{
    __shared__ float As[16][68];
    __shared__ float Bs[16][68];

    const int t  = threadIdx.x;
    const int tx = t & 15;
    const int ty = t >> 4;
    const int m0 = blockIdx.y * 64;
    const int n0 = blockIdx.x * 64;

    float acc[4][4];
#pragma unroll
    for (int i = 0; i < 4; ++i)
#pragma unroll
        for (int j = 0; j < 4; ++j) acc[i][j] = 0.f;

    for (int kt = 0; kt < D_MODEL; kt += 16) {
        __syncthreads();
        {
            const int r  = t >> 2;
            const int c4 = (t & 3) * 4;
            const float4 av = *(const float4*)&A[(size_t)(m0 + r) * D_MODEL + kt + c4];
            As[c4 + 0][r] = av.x;
            As[c4 + 1][r] = av.y;
            As[c4 + 2][r] = av.z;
            As[c4 + 3][r] = av.w;
        }
        {
            const int kr = t >> 4;
            const int c4 = (t & 15) * 4;
            const float4 bv4 = *(const float4*)&W[(size_t)(kt + kr) * D_MODEL + n0 + c4];
            *(float4*)&Bs[kr][c4] = bv4;
        }
        __syncthreads();

#pragma unroll
        for (int k = 0; k < 16; ++k) {
            float a[4], b[4];
#pragma unroll
            for (int i = 0; i < 4; ++i) a[i] = As[k][ty * 4 + i];
#pragma unroll
            for (int j = 0; j < 4; ++j) b[j] = Bs[k][tx * 4 + j];
#pragma unroll
            for (int i = 0; i < 4; ++i)
#pragma unroll
                for (int j = 0; j < 4; ++j) acc[i][j] += a[i] * b[j];
        }
    }

#pragma unroll
    for (int i = 0; i < 4; ++i) {
        const int m = m0 + ty * 4 + i;
#pragma unroll
        for (int j = 0; j < 4; ++j) {
            const int n = n0 + tx * 4 + j;
            const float c = acc[i][j] + bias[n];
            if (MODE == 0) {
                ((float*)outp)[(size_t)m * D_MODEL + n] = c;
            } else {
                const int b  = m >> 11;
                const int s  = m & (SEQ - 1);
                const int h  = n >> 6;
                const int dh = n & 63;
                const ushort u = f2bf(c * scale);
                if (MODE == 1)
                    ((ushort*)outp)[(((size_t)(b * N_HEADS + h)) * SEQ + s) * D_HEAD + dh] = u;
                else
                    ((ushort*)outp)[(((size_t)(b * N_HEADS + h)) * D_HEAD + dh) * SEQ + s] = u;
            }
        }
    }
}

// ---------------------------------------------------------------------------
// Flash attention, bf16 MFMA (16x16x32), fp32 softmax + accumulators.
// Block = 256 thr = 4 waves; wave w owns 16 q-rows of one (b,h).
// Q fragments in registers; K/V fragments direct from global (cache-resident).
// P converted C-layout -> A-layout through a per-wave padded LDS buffer.
// Q comes pre-scaled by 1/sqrt(64) from the GEMM epilogue.
// MFMA layouts (16x16x32_bf16): A/B: row(col)=lane&15, k=(lane>>4)*8+j;
// C/D: col=lane&15, row=(lane>>4)*4+reg  [measured m89/m91].
// ---------------------------------------------------------------------------
__global__ __launch_bounds__(256)
void flash_attn_mfma(const ushort* __restrict__ Q, const ushort* __restrict__ K,
                     const ushort* __restrict__ Vt, float* __restrict__ AO)
{
    __shared__ ushort Ps[4][16][72];   // per-wave P tile, +8 pad: 2-way conflicts only

    const int tid  = threadIdx.x;
    const int w    = tid >> 6;
    const int lane = tid & 63;
    const int l16  = lane & 15;
    const int g    = lane >> 4;
    const int qt   = blockIdx.x;
    const int bh   = blockIdx.y;

    const int q0 = qt * 64 + w * 16;
    const size_t qkbase = (size_t)bh * SEQ * D_HEAD;

    // Q fragments (M=16 rows q0..q0+15, K=64 -> 2 k-steps)
    short8 qf[2];
    {
        const ushort* qp = Q + qkbase + (size_t)(q0 + l16) * D_HEAD + g * 8;
        qf[0] = *(const short8*)(qp);
        qf[1] = *(const short8*)(qp + 32);
    }

    f32x4 o[4];
    float m_r[4], l_r[4];
#pragma unroll
    for (int d = 0; d < 4; ++d) o[d] = f32x4{0.f, 0.f, 0.f, 0.f};
#pragma unroll
    for (int r = 0; r < 4; ++r) { m_r[r] = -INFINITY; l_r[r] = 0.f; }

    for (int kt = 0; kt < SEQ / 64; ++kt) {
        const int k0 = kt * 64;

        // ---- S = Q @ K^T  (16 q x 64 keys), 4 n-tiles x 2 k-steps
        f32x4 s[4];
#pragma unroll
        for (int nt = 0; nt < 4; ++nt) {
            const ushort* kp = K + qkbase + (size_t)(k0 + nt * 16 + l16) * D_HEAD + g * 8;
            f32x4 acc = f32x4{0.f, 0.f, 0.f, 0.f};
            acc = __builtin_amdgcn_mfma_f32_16x16x32_bf16(qf[0], *(const short8*)kp,        acc, 0, 0, 0);
            acc = __builtin_amdgcn_mfma_f32_16x16x32_bf16(qf[1], *(const short8*)(kp + 32), acc, 0, 0, 0);
            s[nt] = acc;
        }

        // ---- online softmax (per C-row r; 16-lane butterfly over key cols)
        float alpha[4];
#pragma unroll
        for (int r = 0; r < 4; ++r) {
            float ml = fmaxf(fmaxf(s[0][r], s[1][r]), fmaxf(s[2][r], s[3][r]));
            ml = fmaxf(ml, __shfl_xor(ml, 1, 64));
            ml = fmaxf(ml, __shfl_xor(ml, 2, 64));
            ml = fmaxf(ml, __shfl_xor(ml, 4, 64));
            ml = fmaxf(ml, __shfl_xor(ml, 8, 64));
            const float mnew = fmaxf(m_r[r], ml);
            alpha[r] = __expf(m_r[r] - mnew);   // first iter: exp(-inf)=0
            m_r[r] = mnew;
            float rs = 0.f;
#pragma unroll
            for (int nt = 0; nt < 4; ++nt) {
                const float p = __expf(s[nt][r] - mnew);
                s[nt][r] = p;
                rs += p;
            }
            rs += __shfl_xor(rs, 1, 64);
            rs += __shfl_xor(rs, 2, 64);
            rs += __shfl_xor(rs, 4, 64);
            rs += __shfl_xor(rs, 8, 64);
            l_r[r] = l_r[r] * alpha[r] + rs;
        }

        // ---- P (C layout) -> LDS bf16 row-major [16 q][64 k]
#pragma unroll
        for (int nt = 0; nt < 4; ++nt)
#pragma unroll
            for (int r = 0; r < 4; ++r)
                Ps[w][g * 4 + r][nt * 16 + l16] = f2bf(s[nt][r]);

        // ---- rescale O
#pragma unroll
        for (int d = 0; d < 4; ++d)
#pragma unroll
            for (int r = 0; r < 4; ++r)
                o[d][r] *= alpha[r];

        // ---- O += P @ V   (A = P from LDS, B = Vt rows: contiguous keys)
#pragma unroll
        for (int ks = 0; ks < 2; ++ks) {
            const short8 pf = *(const short8*)&Ps[w][l16][ks * 32 + g * 8];
#pragma unroll
            for (int dt = 0; dt < 4; ++dt) {
                const ushort* vp = Vt + ((size_t)bh * D_HEAD + dt * 16 + l16) * SEQ + k0 + ks * 32 + g * 8;
                o[dt] = __builtin_amdgcn_mfma_f32_16x16x32_bf16(pf, *(const short8*)vp, o[dt], 0, 0, 0);
            }
        }
    }

    // ---- epilogue: AO[b][s][h*64+d] fp32
    const int b = bh >> 4;
    const int h = bh & 15;
#pragma unroll
    for (int r = 0; r < 4; ++r) {
        const float inv = 1.f / l_r[r];
        const size_t row = (size_t)b * SEQ + q0 + g * 4 + r;
#pragma unroll
        for (int dt = 0; dt < 4; ++dt)
            AO[row * D_MODEL + h * D_HEAD + dt * 16 + l16] = o[dt][r] * inv;
    }
}

// ---------------------------------------------------------------------------
extern "C" void kernel_launch(void* const* d_in, const int* in_sizes, int n_in,
                              void* d_out, int out_size, void* d_ws, size_t ws_size,
                              hipStream_t stream)
{
    const float* x  = (const float*)d_in[0];
    const float* Wq = (const float*)d_in[1];
    const float* bq = (const float*)d_in[2];
    const float* Wk = (const float*)d_in[3];
    const float* bk = (const float*)d_in[4];
    const float* Wv = (const float*)d_in[5];
    const float* bv = (const float*)d_in[6];
    const float* Wo = (const float*)d_in[7];
    const float* bo = (const float*)d_in[8];
    float* out = (float*)d_out;

    const size_t NELT = (size_t)M_TOT * D_MODEL;   // 4M elements
    ushort* Qb  = (ushort*)d_ws;                   // 8 MB bf16 head layout (pre-scaled)
    ushort* Kb  = Qb + NELT;                       // 8 MB bf16 head layout
    ushort* Vtb = Kb + NELT;                       // 8 MB bf16 transposed head layout
    float*  AO  = (float*)(Vtb + NELT);            // 16 MB fp32

    const dim3 gg(D_MODEL / 64, M_TOT / 64);       // 16 x 64
    gemm_bias_kernel<1><<<gg, 256, 0, stream>>>(x, Wq, bq, Qb,  0.125f);
    gemm_bias_kernel<1><<<gg, 256, 0, stream>>>(x, Wk, bk, Kb,  1.0f);
    gemm_bias_kernel<2><<<gg, 256, 0, stream>>>(x, Wv, bv, Vtb, 1.0f);
    flash_attn_mfma<<<dim3(SEQ / 64, BATCH * N_HEADS), 256, 0, stream>>>(Qb, Kb, Vtb, AO);
    gemm_bias_kernel<0><<<gg, 256, 0, stream>>>(AO, Wo, bo, out, 1.0f);
}

// Round 4
// 344.308 us; speedup vs baseline: 10.8851x; 2.2474x over previous
//
#include <hip/hip_runtime.h>
#include <hip/hip_bf16.h>
#include <cmath>

#define D_MODEL 1024
#define N_HEADS 16
#define D_HEAD  64
#define BATCH   2
#define SEQ     2048
#define M_TOT   (BATCH*SEQ)   // 4096

typedef __attribute__((ext_vector_type(8))) short short8;   // 8 bf16 (4 VGPRs)
typedef __attribute__((ext_vector_type(4))) float f32x4;

static __device__ __forceinline__ ushort f2bf(float f) {
    __hip_bfloat16 h = __float2bfloat16(f);   // RNE
    return *reinterpret_cast<ushort*>(&h);
}

static __device__ __forceinline__ void gload_lds16(const void* g, void* l) {
    // 16B-wide global->LDS DMA; LDS dest = wave-uniform base + lane*16
    __builtin_amdgcn_global_load_lds((const __attribute__((address_space(1))) unsigned*)g,
                                     (__attribute__((address_space(3))) unsigned*)l,
                                     16, 0, 0);
}

// ---------------------------------------------------------------------------
// fp32 -> bf16 elementwise (float4 in, ushort4 out)
// ---------------------------------------------------------------------------
__global__ __launch_bounds__(256)
void f32_to_bf16_kernel(const float* __restrict__ in, ushort* __restrict__ out, int n4)
{
    const int i = blockIdx.x * 256 + threadIdx.x;
    if (i < n4) {
        const float4 v = ((const float4*)in)[i];
        ushort4 u;
        u.x = f2bf(v.x); u.y = f2bf(v.y); u.z = f2bf(v.z); u.w = f2bf(v.w);
        ((ushort4*)out)[i] = u;
    }
}

// ---------------------------------------------------------------------------
// W [1024][1024] fp32 row-major -> Wt [N][K] bf16 (transpose + convert)
// 64x64 tiles through LDS; both sides coalesced.
// ---------------------------------------------------------------------------
__global__ __launch_bounds__(256)
void transpose_w_kernel(const float* __restrict__ W, ushort* __restrict__ Wt)
{
    __shared__ float Ts[64][65];
    const int t  = threadIdx.x;
    const int n0 = blockIdx.x * 64;
    const int k0 = blockIdx.y * 64;
    const int rr = t >> 4;          // 0..15
    const int c4 = (t & 15) * 4;    // 0..60

#pragma unroll
    for (int i = 0; i < 4; ++i) {
        const int r = rr + i * 16;
        const float4 v = *(const float4*)&W[(size_t)(k0 + r) * D_MODEL + n0 + c4];
        Ts[r][c4 + 0] = v.x; Ts[r][c4 + 1] = v.y;
        Ts[r][c4 + 2] = v.z; Ts[r][c4 + 3] = v.w;
    }
    __syncthreads();
#pragma unroll
    for (int i = 0; i < 4; ++i) {
        const int nn = rr + i * 16;
        ushort4 u;
        u.x = f2bf(Ts[c4 + 0][nn]); u.y = f2bf(Ts[c4 + 1][nn]);
        u.z = f2bf(Ts[c4 + 2][nn]); u.w = f2bf(Ts[c4 + 3][nn]);
        *(ushort4*)&Wt[(size_t)(n0 + nn) * D_MODEL + k0 + c4] = u;
    }
}

// ---------------------------------------------------------------------------
// V [bh][2048][64] bf16 -> Vt [bh][64][2048] bf16 (transpose)
// ---------------------------------------------------------------------------
__global__ __launch_bounds__(256)
void transpose_v_kernel(const ushort* __restrict__ V, ushort* __restrict__ Vt)
{
    __shared__ ushort Ts[64][68];
    const int t  = threadIdx.x;
    const int s0 = blockIdx.x * 64;
    const int bh = blockIdx.y;
    const int rr = t >> 4;
    const int c4 = (t & 15) * 4;

#pragma unroll
    for (int i = 0; i < 4; ++i) {
        const int r = rr + i * 16;   // s offset
        const ushort4 v = *(const ushort4*)&V[((size_t)bh * SEQ + s0 + r) * D_HEAD + c4];
        Ts[r][c4 + 0] = v.x; Ts[r][c4 + 1] = v.y;
        Ts[r][c4 + 2] = v.z; Ts[r][c4 + 3] = v.w;
    }
    __syncthreads();
#pragma unroll
    for (int i = 0; i < 4; ++i) {
        const int dh = rr + i * 16;
        ushort4 u;
        u.x = Ts[c4 + 0][dh]; u.y = Ts[c4 + 1][dh];
        u.z = Ts[c4 + 2][dh]; u.w = Ts[c4 + 3][dh];
        *(ushort4*)&Vt[((size_t)bh * D_HEAD + dh) * SEQ + s0 + c4] = u;
    }
}

// ---------------------------------------------------------------------------
// bf16 MFMA GEMM: C[M,N] = A[M,K] @ Bt[N,K]^T + bias[N]
// M=4096, N=K=1024. 128x128 tile, BK=64, 256 thr (4 waves, 2x2 of 64x64).
// global_load_lds(16B) staging, linear LDS dest + inverse-swizzled global
// source; ds_read_b128 applies byte ^= (row&7)<<4  (2-way conflicts = free).
// MODE 0: fp32 row-major out.  MODE 1: bf16 head layout [B][H][S][64] *scale.
// ---------------------------------------------------------------------------
template<int MODE>
__global__ __launch_bounds__(256)
void gemm_bf16_mfma(const ushort* __restrict__ A, const ushort* __restrict__ Bt,
                    const float* __restrict__ bias, void* __restrict__ outp,
                    float scale)
{
    __shared__ ushort As[128 * 64];
    __shared__ ushort Bs[128 * 64];

    const int t    = threadIdx.x;
    const int lane = t & 63;
    const int w    = t >> 6;
    const int wr   = w >> 1;        // wave row 0..1
    const int wc   = w & 1;         // wave col 0..1
    const int l16  = lane & 15;
    const int g    = lane >> 4;
    const int m0   = blockIdx.y * 128;
    const int n0   = blockIdx.x * 128;

    f32x4 acc[4][4];
#pragma unroll
    for (int i = 0; i < 4; ++i)
#pragma unroll
        for (int j = 0; j < 4; ++j) acc[i][j] = f32x4{0.f, 0.f, 0.f, 0.f};

    // per-thread staging coords (linear LDS byte b -> pre-swizzled global src)
    // b = (it*256 + t)*16 ; row = b>>7 ; c = b&127 ; src_col_byte = c ^ ((row&7)<<4)
    for (int kt = 0; kt < D_MODEL; kt += 64) {
        __syncthreads();   // previous compute done before overwrite
        const ushort* Ag = A  + (size_t)m0 * D_MODEL + kt;
        const ushort* Bg = Bt + (size_t)n0 * D_MODEL + kt;
#pragma unroll
        for (int it = 0; it < 4; ++it) {
            const int b   = (it * 256 + t) * 16;
            const int row = b >> 7;
            const int src = (b & 127) ^ ((row & 7) << 4);
            const int lof = (it * 256 + (t & ~63)) * 8;   // ushort units, wave-uniform
            gload_lds16(Ag + (size_t)row * D_MODEL + (src >> 1), As + lof);
            gload_lds16(Bg + (size_t)row * D_MODEL + (src >> 1), Bs + lof);
        }
        __syncthreads();   // vmcnt(0) drained by barrier

#pragma unroll
        for (int kh = 0; kh < 2; ++kh) {
            short8 a[4], bfr[4];
#pragma unroll
            for (int fm = 0; fm < 4; ++fm) {
                const int row  = wr * 64 + fm * 16 + l16;
                const int byte = row * 128 + (((kh << 6) | (g << 4)) ^ ((row & 7) << 4));
                a[fm] = *(const short8*)((const char*)As + byte);
            }
#pragma unroll
            for (int fn = 0; fn < 4; ++fn) {
                const int row  = wc * 64 + fn * 16 + l16;
                const int byte = row * 128 + (((kh << 6) | (g << 4)) ^ ((row & 7) << 4));
                bfr[fn] = *(const short8*)((const char*)Bs + byte);
            }
#pragma unroll
            for (int fm = 0; fm < 4; ++fm)
#pragma unroll
                for (int fn = 0; fn < 4; ++fn)
                    acc[fm][fn] = __builtin_amdgcn_mfma_f32_16x16x32_bf16(a[fm], bfr[fn], acc[fm][fn], 0, 0, 0);
        }
    }

    // epilogue (C/D: col = lane&15, row = (lane>>4)*4 + reg)
#pragma unroll
    for (int fm = 0; fm < 4; ++fm) {
        const int mb = m0 + wr * 64 + fm * 16 + g * 4;
#pragma unroll
        for (int fn = 0; fn < 4; ++fn) {
            const int n  = n0 + wc * 64 + fn * 16 + l16;
            const float bn = bias[n];
#pragma unroll
            for (int r = 0; r < 4; ++r) {
                const float c = acc[fm][fn][r] + bn;
                const int m = mb + r;
                if (MODE == 0) {
                    ((float*)outp)[(size_t)m * D_MODEL + n] = c;
                } else {
                    const int bb = m >> 11;
                    const int s  = m & (SEQ - 1);
                    const int h  = n >> 6;
                    const int dh = n & 63;
                    ((ushort*)outp)[(((size_t)(bb * N_HEADS + h)) * SEQ + s) * D_HEAD + dh] = f2bf(c * scale);
                }
            }
        }
    }
}

// ---------------------------------------------------------------------------
// Flash attention, bf16 MFMA (16x16x32), fp32 softmax + accumulators.
// Block = 256 thr = 4 waves; wave w owns 16 q-rows of one (b,h).
// Output written as bf16 into AO [B][S][H*64] (feeds o-projection GEMM).
// ---------------------------------------------------------------------------
__global__ __launch_bounds__(256)
void flash_attn_mfma(const ushort* __restrict__ Q, const ushort* __restrict__ K,
                     const ushort* __restrict__ Vt, ushort* __restrict__ AO)
{
    __shared__ ushort Ps[4][16][72];

    const int tid  = threadIdx.x;
    const int w    = tid >> 6;
    const int lane = tid & 63;
    const int l16  = lane & 15;
    const int g    = lane >> 4;
    const int qt   = blockIdx.x;
    const int bh   = blockIdx.y;

    const int q0 = qt * 64 + w * 16;
    const size_t qkbase = (size_t)bh * SEQ * D_HEAD;

    short8 qf[2];
    {
        const ushort* qp = Q + qkbase + (size_t)(q0 + l16) * D_HEAD + g * 8;
        qf[0] = *(const short8*)(qp);
        qf[1] = *(const short8*)(qp + 32);
    }

    f32x4 o[4];
    float m_r[4], l_r[4];
#pragma unroll
    for (int d = 0; d < 4; ++d) o[d] = f32x4{0.f, 0.f, 0.f, 0.f};
#pragma unroll
    for (int r = 0; r < 4; ++r) { m_r[r] = -INFINITY; l_r[r] = 0.f; }

    for (int kt = 0; kt < SEQ / 64; ++kt) {
        const int k0 = kt * 64;

        f32x4 s[4];
#pragma unroll
        for (int nt = 0; nt < 4; ++nt) {
            const ushort* kp = K + qkbase + (size_t)(k0 + nt * 16 + l16) * D_HEAD + g * 8;
            f32x4 acc = f32x4{0.f, 0.f, 0.f, 0.f};
            acc = __builtin_amdgcn_mfma_f32_16x16x32_bf16(qf[0], *(const short8*)kp,        acc, 0, 0, 0);
            acc = __builtin_amdgcn_mfma_f32_16x16x32_bf16(qf[1], *(const short8*)(kp + 32), acc, 0, 0, 0);
            s[nt] = acc;
        }

        float alpha[4];
#pragma unroll
        for (int r = 0; r < 4; ++r) {
            float ml = fmaxf(fmaxf(s[0][r], s[1][r]), fmaxf(s[2][r], s[3][r]));
            ml = fmaxf(ml, __shfl_xor(ml, 1, 64));
            ml = fmaxf(ml, __shfl_xor(ml, 2, 64));
            ml = fmaxf(ml, __shfl_xor(ml, 4, 64));
            ml = fmaxf(ml, __shfl_xor(ml, 8, 64));
            const float mnew = fmaxf(m_r[r], ml);
            alpha[r] = __expf(m_r[r] - mnew);
            m_r[r] = mnew;
            float rs = 0.f;
#pragma unroll
            for (int nt = 0; nt < 4; ++nt) {
                const float p = __expf(s[nt][r] - mnew);
                s[nt][r] = p;
                rs += p;
            }
            rs += __shfl_xor(rs, 1, 64);
            rs += __shfl_xor(rs, 2, 64);
            rs += __shfl_xor(rs, 4, 64);
            rs += __shfl_xor(rs, 8, 64);
            l_r[r] = l_r[r] * alpha[r] + rs;
        }

#pragma unroll
        for (int nt = 0; nt < 4; ++nt)
#pragma unroll
            for (int r = 0; r < 4; ++r)
                Ps[w][g * 4 + r][nt * 16 + l16] = f2bf(s[nt][r]);

#pragma unroll
        for (int d = 0; d < 4; ++d)
#pragma unroll
            for (int r = 0; r < 4; ++r)
                o[d][r] *= alpha[r];

#pragma unroll
        for (int ks = 0; ks < 2; ++ks) {
            const short8 pf = *(const short8*)&Ps[w][l16][ks * 32 + g * 8];
#pragma unroll
            for (int dt = 0; dt < 4; ++dt) {
                const ushort* vp = Vt + ((size_t)bh * D_HEAD + dt * 16 + l16) * SEQ + k0 + ks * 32 + g * 8;
                o[dt] = __builtin_amdgcn_mfma_f32_16x16x32_bf16(pf, *(const short8*)vp, o[dt], 0, 0, 0);
            }
        }
    }

    const int b = bh >> 4;
    const int h = bh & 15;
#pragma unroll
    for (int r = 0; r < 4; ++r) {
        const float inv = 1.f / l_r[r];
        const size_t row = (size_t)b * SEQ + q0 + g * 4 + r;
#pragma unroll
        for (int dt = 0; dt < 4; ++dt)
            AO[row * D_MODEL + h * D_HEAD + dt * 16 + l16] = f2bf(o[dt][r] * inv);
    }
}

// ---------------------------------------------------------------------------
extern "C" void kernel_launch(void* const* d_in, const int* in_sizes, int n_in,
                              void* d_out, int out_size, void* d_ws, size_t ws_size,
                              hipStream_t stream)
{
    const float* x  = (const float*)d_in[0];
    const float* Wq = (const float*)d_in[1];
    const float* bq = (const float*)d_in[2];
    const float* Wk = (const float*)d_in[3];
    const float* bk = (const float*)d_in[4];
    const float* Wv = (const float*)d_in[5];
    const float* bv = (const float*)d_in[6];
    const float* Wo = (const float*)d_in[7];
    const float* bo = (const float*)d_in[8];
    float* out = (float*)d_out;

    const size_t NELT = (size_t)M_TOT * D_MODEL;     // 4M
    const size_t WELT = (size_t)D_MODEL * D_MODEL;   // 1M
    ushort* xb  = (ushort*)d_ws;        // [4096][1024] bf16; reused as Vt later
    ushort* Wqt = xb + NELT;
    ushort* Wkt = Wqt + WELT;
    ushort* Wvt = Wkt + WELT;
    ushort* Wot = Wvt + WELT;
    ushort* Qb  = xb + 2 * NELT;        // head layout, pre-scaled by 0.125
    ushort* Kb  = xb + 3 * NELT;        // head layout
    ushort* Vb  = xb + 4 * NELT;        // head layout; reused as AO later
    ushort* Vtb = xb;                   // [bh][64][2048] (aliases xb, written after QKV GEMMs)
    ushort* AOb = Vb;                   // [4096][1024]   (aliases Vb, written after V transpose)

    // 1. convert x to bf16
    f32_to_bf16_kernel<<<dim3((M_TOT * D_MODEL / 4 + 255) / 256), 256, 0, stream>>>(x, xb, M_TOT * D_MODEL / 4);
    // 2. transpose+convert weights to [N][K] bf16
    const dim3 gt(D_MODEL / 64, D_MODEL / 64);
    transpose_w_kernel<<<gt, 256, 0, stream>>>(Wq, Wqt);
    transpose_w_kernel<<<gt, 256, 0, stream>>>(Wk, Wkt);
    transpose_w_kernel<<<gt, 256, 0, stream>>>(Wv, Wvt);
    transpose_w_kernel<<<gt, 256, 0, stream>>>(Wo, Wot);
    // 3. QKV projections (bf16 MFMA)
    const dim3 gg(D_MODEL / 128, M_TOT / 128);   // 8 x 32 = 256 blocks
    gemm_bf16_mfma<1><<<gg, 256, 0, stream>>>(xb, Wqt, bq, Qb, 0.125f);
    gemm_bf16_mfma<1><<<gg, 256, 0, stream>>>(xb, Wkt, bk, Kb, 1.0f);
    gemm_bf16_mfma<1><<<gg, 256, 0, stream>>>(xb, Wvt, bv, Vb, 1.0f);
    // 4. transpose V for PV (xb is dead now)
    transpose_v_kernel<<<dim3(SEQ / 64, BATCH * N_HEADS), 256, 0, stream>>>(Vb, Vtb);
    // 5. attention (Vb dead -> AO reuses it)
    flash_attn_mfma<<<dim3(SEQ / 64, BATCH * N_HEADS), 256, 0, stream>>>(Qb, Kb, Vtb, AOb);
    // 6. output projection (fp32 out)
    gemm_bf16_mfma<0><<<gg, 256, 0, stream>>>(AOb, Wot, bo, out, 1.0f);
}

// Round 5
// 309.046 us; speedup vs baseline: 12.1271x; 1.1141x over previous
//
#include <hip/hip_runtime.h>
#include <hip/hip_bf16.h>
#include <cmath>

#define D_MODEL 1024
#define N_HEADS 16
#define D_HEAD  64
#define BATCH   2
#define SEQ     2048
#define M_TOT   (BATCH*SEQ)   // 4096

typedef __attribute__((ext_vector_type(8))) short short8;   // 8 bf16 (4 VGPRs)
typedef __attribute__((ext_vector_type(4))) float f32x4;

static __device__ __forceinline__ ushort f2bf(float f) {
    __hip_bfloat16 h = __float2bfloat16(f);   // RNE
    return *reinterpret_cast<ushort*>(&h);
}

static __device__ __forceinline__ void gload_lds16(const void* g, void* l) {
    __builtin_amdgcn_global_load_lds((const __attribute__((address_space(1))) unsigned*)g,
                                     (__attribute__((address_space(3))) unsigned*)l,
                                     16, 0, 0);
}

// ---------------------------------------------------------------------------
// fp32 -> bf16 elementwise (float4 in, ushort4 out)
// ---------------------------------------------------------------------------
__global__ __launch_bounds__(256)
void f32_to_bf16_kernel(const float* __restrict__ in, ushort* __restrict__ out, int n4)
{
    const int i = blockIdx.x * 256 + threadIdx.x;
    if (i < n4) {
        const float4 v = ((const float4*)in)[i];
        ushort4 u;
        u.x = f2bf(v.x); u.y = f2bf(v.y); u.z = f2bf(v.z); u.w = f2bf(v.w);
        ((ushort4*)out)[i] = u;
    }
}

// ---------------------------------------------------------------------------
// All four weights [1024][1024] fp32 -> Wt [N][K] bf16 (transpose + convert).
// blockIdx.z selects the weight; outputs are contiguous at Wt0 + z*1M.
// ---------------------------------------------------------------------------
__global__ __launch_bounds__(256)
void transpose_w4_kernel(const float* __restrict__ W0, const float* __restrict__ W1,
                         const float* __restrict__ W2, const float* __restrict__ W3,
                         ushort* __restrict__ Wt0)
{
    __shared__ float Ts[64][65];
    const int z = blockIdx.z;
    const float* W = (z == 0) ? W0 : (z == 1) ? W1 : (z == 2) ? W2 : W3;
    ushort* Wt = Wt0 + (size_t)z * D_MODEL * D_MODEL;

    const int t  = threadIdx.x;
    const int n0 = blockIdx.x * 64;
    const int k0 = blockIdx.y * 64;
    const int rr = t >> 4;
    const int c4 = (t & 15) * 4;

#pragma unroll
    for (int i = 0; i < 4; ++i) {
        const int r = rr + i * 16;
        const float4 v = *(const float4*)&W[(size_t)(k0 + r) * D_MODEL + n0 + c4];
        Ts[r][c4 + 0] = v.x; Ts[r][c4 + 1] = v.y;
        Ts[r][c4 + 2] = v.z; Ts[r][c4 + 3] = v.w;
    }
    __syncthreads();
#pragma unroll
    for (int i = 0; i < 4; ++i) {
        const int nn = rr + i * 16;
        ushort4 u;
        u.x = f2bf(Ts[c4 + 0][nn]); u.y = f2bf(Ts[c4 + 1][nn]);
        u.z = f2bf(Ts[c4 + 2][nn]); u.w = f2bf(Ts[c4 + 3][nn]);
        *(ushort4*)&Wt[(size_t)(n0 + nn) * D_MODEL + k0 + c4] = u;
    }
}

// ---------------------------------------------------------------------------
// V [bh][2048][64] bf16 -> Vt [bh][64][2048] bf16 (transpose)
// ---------------------------------------------------------------------------
__global__ __launch_bounds__(256)
void transpose_v_kernel(const ushort* __restrict__ V, ushort* __restrict__ Vt)
{
    __shared__ ushort Ts[64][68];
    const int t  = threadIdx.x;
    const int s0 = blockIdx.x * 64;
    const int bh = blockIdx.y;
    const int rr = t >> 4;
    const int c4 = (t & 15) * 4;

#pragma unroll
    for (int i = 0; i < 4; ++i) {
        const int r = rr + i * 16;
        const ushort4 v = *(const ushort4*)&V[((size_t)bh * SEQ + s0 + r) * D_HEAD + c4];
        Ts[r][c4 + 0] = v.x; Ts[r][c4 + 1] = v.y;
        Ts[r][c4 + 2] = v.z; Ts[r][c4 + 3] = v.w;
    }
    __syncthreads();
#pragma unroll
    for (int i = 0; i < 4; ++i) {
        const int dh = rr + i * 16;
        ushort4 u;
        u.x = Ts[c4 + 0][dh]; u.y = Ts[c4 + 1][dh];
        u.z = Ts[c4 + 2][dh]; u.w = Ts[c4 + 3][dh];
        *(ushort4*)&Vt[((size_t)bh * D_HEAD + dh) * SEQ + s0 + c4] = u;
    }
}

// ---------------------------------------------------------------------------
// Merged QKV GEMM: C[M, 0..3071] = xb[M,K] @ Wqkv_t[N,K]^T + bias, bf16 MFMA.
// 128x128 tile, BK=64, 4 waves. proj = n>>10 selects Q/K/V; Q scaled 0.125.
// Output: bf16 head layout at QKV + proj*NELT.
// ---------------------------------------------------------------------------
__global__ __launch_bounds__(256)
void gemm_qkv_mfma(const ushort* __restrict__ A, const ushort* __restrict__ Bt,
                   const float* __restrict__ bq, const float* __restrict__ bk,
                   const float* __restrict__ bv, ushort* __restrict__ QKV)
{
    __shared__ ushort As[128 * 64];
    __shared__ ushort Bs[128 * 64];

    const int t    = threadIdx.x;
    const int lane = t & 63;
    const int w    = t >> 6;
    const int wr   = w >> 1;
    const int wc   = w & 1;
    const int l16  = lane & 15;
    const int g    = lane >> 4;
    const int m0   = blockIdx.y * 128;
    const int n0   = blockIdx.x * 128;

    f32x4 acc[4][4];
#pragma unroll
    for (int i = 0; i < 4; ++i)
#pragma unroll
        for (int j = 0; j < 4; ++j) acc[i][j] = f32x4{0.f, 0.f, 0.f, 0.f};

    for (int kt = 0; kt < D_MODEL; kt += 64) {
        __syncthreads();
        const ushort* Ag = A  + (size_t)m0 * D_MODEL + kt;
        const ushort* Bg = Bt + (size_t)n0 * D_MODEL + kt;
#pragma unroll
        for (int it = 0; it < 4; ++it) {
            const int b   = (it * 256 + t) * 16;
            const int row = b >> 7;
            const int src = (b & 127) ^ ((row & 7) << 4);
            const int lof = (it * 256 + (t & ~63)) * 8;
            gload_lds16(Ag + (size_t)row * D_MODEL + (src >> 1), As + lof);
            gload_lds16(Bg + (size_t)row * D_MODEL + (src >> 1), Bs + lof);
        }
        __syncthreads();

#pragma unroll
        for (int kh = 0; kh < 2; ++kh) {
            short8 a[4], bfr[4];
#pragma unroll
            for (int fm = 0; fm < 4; ++fm) {
                const int row  = wr * 64 + fm * 16 + l16;
                const int byte = row * 128 + (((kh << 6) | (g << 4)) ^ ((row & 7) << 4));
                a[fm] = *(const short8*)((const char*)As + byte);
            }
#pragma unroll
            for (int fn = 0; fn < 4; ++fn) {
                const int row  = wc * 64 + fn * 16 + l16;
                const int byte = row * 128 + (((kh << 6) | (g << 4)) ^ ((row & 7) << 4));
                bfr[fn] = *(const short8*)((const char*)Bs + byte);
            }
#pragma unroll
            for (int fm = 0; fm < 4; ++fm)
#pragma unroll
                for (int fn = 0; fn < 4; ++fn)
                    acc[fm][fn] = __builtin_amdgcn_mfma_f32_16x16x32_bf16(a[fm], bfr[fn], acc[fm][fn], 0, 0, 0);
        }
    }

#pragma unroll
    for (int fm = 0; fm < 4; ++fm) {
        const int mb = m0 + wr * 64 + fm * 16 + g * 4;
#pragma unroll
        for (int fn = 0; fn < 4; ++fn) {
            const int n    = n0 + wc * 64 + fn * 16 + l16;
            const int proj = n >> 10;
            const int nn   = n & 1023;
            const float bn = (proj == 0) ? bq[nn] : (proj == 1) ? bk[nn] : bv[nn];
            const float sc = (proj == 0) ? 0.125f : 1.0f;
            ushort* outp = QKV + (size_t)proj * M_TOT * D_MODEL;
#pragma unroll
            for (int r = 0; r < 4; ++r) {
                const float c = (acc[fm][fn][r] + bn) * sc;
                const int m  = mb + r;
                const int bb = m >> 11;
                const int s  = m & (SEQ - 1);
                const int h  = nn >> 6;
                const int dh = nn & 63;
                outp[(((size_t)(bb * N_HEADS + h)) * SEQ + s) * D_HEAD + dh] = f2bf(c);
            }
        }
    }
}

// ---------------------------------------------------------------------------
// Output-projection GEMM (bf16 MFMA, fp32 out): out = AO @ Wot^T + bo
// ---------------------------------------------------------------------------
__global__ __launch_bounds__(256)
void gemm_out_mfma(const ushort* __restrict__ A, const ushort* __restrict__ Bt,
                   const float* __restrict__ bias, float* __restrict__ outp)
{
    __shared__ ushort As[128 * 64];
    __shared__ ushort Bs[128 * 64];

    const int t    = threadIdx.x;
    const int lane = t & 63;
    const int w    = t >> 6;
    const int wr   = w >> 1;
    const int wc   = w & 1;
    const int l16  = lane & 15;
    const int g    = lane >> 4;
    const int m0   = blockIdx.y * 128;
    const int n0   = blockIdx.x * 128;

    f32x4 acc[4][4];
#pragma unroll
    for (int i = 0; i < 4; ++i)
#pragma unroll
        for (int j = 0; j < 4; ++j) acc[i][j] = f32x4{0.f, 0.f, 0.f, 0.f};

    for (int kt = 0; kt < D_MODEL; kt += 64) {
        __syncthreads();
        const ushort* Ag = A  + (size_t)m0 * D_MODEL + kt;
        const ushort* Bg = Bt + (size_t)n0 * D_MODEL + kt;
#pragma unroll
        for (int it = 0; it < 4; ++it) {
            const int b   = (it * 256 + t) * 16;
            const int row = b >> 7;
            const int src = (b & 127) ^ ((row & 7) << 4);
            const int lof = (it * 256 + (t & ~63)) * 8;
            gload_lds16(Ag + (size_t)row * D_MODEL + (src >> 1), As + lof);
            gload_lds16(Bg + (size_t)row * D_MODEL + (src >> 1), Bs + lof);
        }
        __syncthreads();

#pragma unroll
        for (int kh = 0; kh < 2; ++kh) {
            short8 a[4], bfr[4];
#pragma unroll
            for (int fm = 0; fm < 4; ++fm) {
                const int row  = wr * 64 + fm * 16 + l16;
                const int byte = row * 128 + (((kh << 6) | (g << 4)) ^ ((row & 7) << 4));
                a[fm] = *(const short8*)((const char*)As + byte);
            }
#pragma unroll
            for (int fn = 0; fn < 4; ++fn) {
                const int row  = wc * 64 + fn * 16 + l16;
                const int byte = row * 128 + (((kh << 6) | (g << 4)) ^ ((row & 7) << 4));
                bfr[fn] = *(const short8*)((const char*)Bs + byte);
            }
#pragma unroll
            for (int fm = 0; fm < 4; ++fm)
#pragma unroll
                for (int fn = 0; fn < 4; ++fn)
                    acc[fm][fn] = __builtin_amdgcn_mfma_f32_16x16x32_bf16(a[fm], bfr[fn], acc[fm][fn], 0, 0, 0);
        }
    }

#pragma unroll
    for (int fm = 0; fm < 4; ++fm) {
        const int mb = m0 + wr * 64 + fm * 16 + g * 4;
#pragma unroll
        for (int fn = 0; fn < 4; ++fn) {
            const int n  = n0 + wc * 64 + fn * 16 + l16;
            const float bn = bias[n];
#pragma unroll
            for (int r = 0; r < 4; ++r)
                outp[(size_t)(mb + r) * D_MODEL + n] = acc[fm][fn][r] + bn;
        }
    }
}

// ---------------------------------------------------------------------------
// Flash attention, swapped-QK^T bf16 MFMA, row-local softmax.
// Block = 4 waves; wave owns 16 q-rows of one (b,h). Per K-tile (64 keys):
//   S^T = mfma(K_frag, Q_frag): lane (l16,g) holds P[q=l16][k=nt*16+g*4+r]
//   -> row reduce = 15 local ops + 2 shfl_xor(16/32) instead of 32 butterflies.
// Next K-tile prefetched during softmax; V loads issued before softmax.
// P -> LDS (ushort4 packed) -> read back in A-layout for unswapped PV.
// ---------------------------------------------------------------------------
__global__ __launch_bounds__(256)
void flash_attn_mfma(const ushort* __restrict__ Q, const ushort* __restrict__ K,
                     const ushort* __restrict__ Vt, ushort* __restrict__ AO)
{
    __shared__ ushort Ps[4][16][72];

    const int tid  = threadIdx.x;
    const int w    = tid >> 6;
    const int lane = tid & 63;
    const int l16  = lane & 15;
    const int g    = lane >> 4;
    const int qt   = blockIdx.x;
    const int bh   = blockIdx.y;

    const int q0 = qt * 64 + w * 16;
    const size_t qkbase = (size_t)bh * SEQ * D_HEAD;

    // Q fragment (B operand): lane holds Q[q=l16][d=g*8..+7]
    short8 qf[2];
    {
        const ushort* qp = Q + qkbase + (size_t)(q0 + l16) * D_HEAD + g * 8;
        qf[0] = *(const short8*)(qp);
        qf[1] = *(const short8*)(qp + 32);
    }

    const ushort* kp0 = K + qkbase + (size_t)l16 * D_HEAD + g * 8;           // + key*64
    const ushort* vp0 = Vt + ((size_t)bh * D_HEAD + l16) * SEQ + g * 8;      // + dt*16*SEQ + k

    f32x4 o[4];
#pragma unroll
    for (int d = 0; d < 4; ++d) o[d] = f32x4{0.f, 0.f, 0.f, 0.f};
    float m_r = -INFINITY, l_r = 0.f;

    // preload K tile 0 fragments (A operand): lane holds K[key=nt*16+l16][d=g*8..+7]
    short8 kf[4][2];
#pragma unroll
    for (int nt = 0; nt < 4; ++nt) {
        kf[nt][0] = *(const short8*)(kp0 + (size_t)(nt * 16) * D_HEAD);
        kf[nt][1] = *(const short8*)(kp0 + (size_t)(nt * 16) * D_HEAD + 32);
    }

    for (int kt = 0; kt < SEQ / 64; ++kt) {
        const int k0 = kt * 64;

        // ---- S^T = K @ Q^T : st[nt][r] = P[q=l16][key=nt*16+g*4+r] (pre-exp)
        f32x4 st[4];
#pragma unroll
        for (int nt = 0; nt < 4; ++nt) {
            f32x4 a = f32x4{0.f, 0.f, 0.f, 0.f};
            a = __builtin_amdgcn_mfma_f32_16x16x32_bf16(kf[nt][0], qf[0], a, 0, 0, 0);
            a = __builtin_amdgcn_mfma_f32_16x16x32_bf16(kf[nt][1], qf[1], a, 0, 0, 0);
            st[nt] = a;
        }

        // ---- prefetch next K tile (hidden under softmax)
        if (kt < SEQ / 64 - 1) {
#pragma unroll
            for (int nt = 0; nt < 4; ++nt) {
                kf[nt][0] = *(const short8*)(kp0 + (size_t)(k0 + 64 + nt * 16) * D_HEAD);
                kf[nt][1] = *(const short8*)(kp0 + (size_t)(k0 + 64 + nt * 16) * D_HEAD + 32);
            }
        }

        // ---- V fragments for this tile (B operand of PV)
        short8 vf[4][2];
#pragma unroll
        for (int dt = 0; dt < 4; ++dt) {
            vf[dt][0] = *(const short8*)(vp0 + (size_t)(dt * 16) * SEQ + k0);
            vf[dt][1] = *(const short8*)(vp0 + (size_t)(dt * 16) * SEQ + k0 + 32);
        }

        // ---- softmax: row q=l16, 16 local values + 2-lane-group combine
        float ml = st[0][0];
#pragma unroll
        for (int nt = 0; nt < 4; ++nt)
#pragma unroll
            for (int r = 0; r < 4; ++r) ml = fmaxf(ml, st[nt][r]);
        ml = fmaxf(ml, __shfl_xor(ml, 16, 64));
        ml = fmaxf(ml, __shfl_xor(ml, 32, 64));
        const float mnew = fmaxf(m_r, ml);
        const float alpha = __expf(m_r - mnew);
        m_r = mnew;
        float rs = 0.f;
#pragma unroll
        for (int nt = 0; nt < 4; ++nt)
#pragma unroll
            for (int r = 0; r < 4; ++r) {
                const float p = __expf(st[nt][r] - mnew);
                st[nt][r] = p;
                rs += p;
            }
        rs += __shfl_xor(rs, 16, 64);
        rs += __shfl_xor(rs, 32, 64);
        l_r = l_r * alpha + rs;

        // ---- P -> LDS, packed 4 keys per write: Ps[q=l16][nt*16+g*4 .. +3]
#pragma unroll
        for (int nt = 0; nt < 4; ++nt) {
            ushort4 pk;
            pk.x = f2bf(st[nt][0]); pk.y = f2bf(st[nt][1]);
            pk.z = f2bf(st[nt][2]); pk.w = f2bf(st[nt][3]);
            *(ushort4*)&Ps[w][l16][nt * 16 + g * 4] = pk;
        }

        // ---- redistribute alpha to o-rows (o row = q = g*4+r)
        float ar[4];
#pragma unroll
        for (int r = 0; r < 4; ++r) ar[r] = __shfl(alpha, g * 4 + r, 64);
#pragma unroll
        for (int dt = 0; dt < 4; ++dt)
#pragma unroll
            for (int r = 0; r < 4; ++r) o[dt][r] *= ar[r];

        // ---- O += P @ V (unswapped: A=P from LDS, B=V^T fragments)
#pragma unroll
        for (int ks = 0; ks < 2; ++ks) {
            const short8 pf = *(const short8*)&Ps[w][l16][ks * 32 + g * 8];
#pragma unroll
            for (int dt = 0; dt < 4; ++dt)
                o[dt] = __builtin_amdgcn_mfma_f32_16x16x32_bf16(pf, vf[dt][ks], o[dt], 0, 0, 0);
        }
    }

    // ---- epilogue: AO[b][s][h*64+d] bf16 ; l for row q=g*4+r via shfl
    float lr_row[4];
#pragma unroll
    for (int r = 0; r < 4; ++r) lr_row[r] = __shfl(l_r, g * 4 + r, 64);
    const int b = bh >> 4;
    const int h = bh & 15;
#pragma unroll
    for (int r = 0; r < 4; ++r) {
        const float inv = 1.f / lr_row[r];
        const size_t row = (size_t)b * SEQ + q0 + g * 4 + r;
#pragma unroll
        for (int dt = 0; dt < 4; ++dt)
            AO[row * D_MODEL + h * D_HEAD + dt * 16 + l16] = f2bf(o[dt][r] * inv);
    }
}

// ---------------------------------------------------------------------------
extern "C" void kernel_launch(void* const* d_in, const int* in_sizes, int n_in,
                              void* d_out, int out_size, void* d_ws, size_t ws_size,
                              hipStream_t stream)
{
    const float* x  = (const float*)d_in[0];
    const float* Wq = (const float*)d_in[1];
    const float* bq = (const float*)d_in[2];
    const float* Wk = (const float*)d_in[3];
    const float* bk = (const float*)d_in[4];
    const float* Wv = (const float*)d_in[5];
    const float* bv = (const float*)d_in[6];
    const float* Wo = (const float*)d_in[7];
    const float* bo = (const float*)d_in[8];
    float* out = (float*)d_out;

    const size_t NELT = (size_t)M_TOT * D_MODEL;     // 4M
    const size_t WELT = (size_t)D_MODEL * D_MODEL;   // 1M
    ushort* xb  = (ushort*)d_ws;        // [4096][1024] bf16; reused as Vt later
    ushort* Wqt = xb + NELT;            // Wqt/Wkt/Wvt/Wot contiguous [N][K]
    ushort* Wot = Wqt + 3 * WELT;
    ushort* Qb  = xb + 2 * NELT;        // Qb/Kb/Vb contiguous head layout
    ushort* Vb  = xb + 4 * NELT;
    ushort* Vtb = xb;                   // aliases xb (dead after QKV GEMM)
    ushort* AOb = Vb;                   // aliases Vb (dead after V transpose)

    f32_to_bf16_kernel<<<dim3((M_TOT * D_MODEL / 4 + 255) / 256), 256, 0, stream>>>(x, xb, M_TOT * D_MODEL / 4);
    transpose_w4_kernel<<<dim3(D_MODEL / 64, D_MODEL / 64, 4), 256, 0, stream>>>(Wq, Wk, Wv, Wo, Wqt);
    gemm_qkv_mfma<<<dim3(3 * D_MODEL / 128, M_TOT / 128), 256, 0, stream>>>(xb, Wqt, bq, bk, bv, Qb);
    transpose_v_kernel<<<dim3(SEQ / 64, BATCH * N_HEADS), 256, 0, stream>>>(Vb, Vtb);
    flash_attn_mfma<<<dim3(SEQ / 64, BATCH * N_HEADS), 256, 0, stream>>>(Qb, Qb + NELT, Vtb, AOb);
    gemm_out_mfma<<<dim3(D_MODEL / 128, M_TOT / 128), 256, 0, stream>>>(AOb, Wot, bo, out);
}

// Round 6
// 149.201 us; speedup vs baseline: 25.1193x; 2.0713x over previous
//
#include <hip/hip_runtime.h>
#include <hip/hip_bf16.h>
#include <cmath>

#define D_MODEL 1024
#define N_HEADS 16
#define D_HEAD  64
#define BATCH   2
#define SEQ     2048
#define M_TOT   (BATCH*SEQ)   // 4096

typedef __attribute__((ext_vector_type(8))) short short8;   // 8 bf16 (4 VGPRs)
typedef __attribute__((ext_vector_type(4))) float f32x4;

static __device__ __forceinline__ ushort f2bf(float f) {
    __hip_bfloat16 h = __float2bfloat16(f);   // RNE
    return *reinterpret_cast<ushort*>(&h);
}

static __device__ __forceinline__ void gload_lds16(const void* g, void* l) {
    __builtin_amdgcn_global_load_lds((const __attribute__((address_space(1))) unsigned*)g,
                                     (__attribute__((address_space(3))) unsigned*)l,
                                     16, 0, 0);
}

// ---------------------------------------------------------------------------
// fp32 -> bf16 elementwise (float4 in, ushort4 out)
// ---------------------------------------------------------------------------
__global__ __launch_bounds__(256)
void f32_to_bf16_kernel(const float* __restrict__ in, ushort* __restrict__ out, int n4)
{
    const int i = blockIdx.x * 256 + threadIdx.x;
    if (i < n4) {
        const float4 v = ((const float4*)in)[i];
        ushort4 u;
        u.x = f2bf(v.x); u.y = f2bf(v.y); u.z = f2bf(v.z); u.w = f2bf(v.w);
        ((ushort4*)out)[i] = u;
    }
}

// ---------------------------------------------------------------------------
// All four weights [1024][1024] fp32 -> Wt [N][K] bf16 (transpose + convert).
// ---------------------------------------------------------------------------
__global__ __launch_bounds__(256)
void transpose_w4_kernel(const float* __restrict__ W0, const float* __restrict__ W1,
                         const float* __restrict__ W2, const float* __restrict__ W3,
                         ushort* __restrict__ Wt0)
{
    __shared__ float Ts[64][65];
    const int z = blockIdx.z;
    const float* W = (z == 0) ? W0 : (z == 1) ? W1 : (z == 2) ? W2 : W3;
    ushort* Wt = Wt0 + (size_t)z * D_MODEL * D_MODEL;

    const int t  = threadIdx.x;
    const int n0 = blockIdx.x * 64;
    const int k0 = blockIdx.y * 64;
    const int rr = t >> 4;
    const int c4 = (t & 15) * 4;

#pragma unroll
    for (int i = 0; i < 4; ++i) {
        const int r = rr + i * 16;
        const float4 v = *(const float4*)&W[(size_t)(k0 + r) * D_MODEL + n0 + c4];
        Ts[r][c4 + 0] = v.x; Ts[r][c4 + 1] = v.y;
        Ts[r][c4 + 2] = v.z; Ts[r][c4 + 3] = v.w;
    }
    __syncthreads();
#pragma unroll
    for (int i = 0; i < 4; ++i) {
        const int nn = rr + i * 16;
        ushort4 u;
        u.x = f2bf(Ts[c4 + 0][nn]); u.y = f2bf(Ts[c4 + 1][nn]);
        u.z = f2bf(Ts[c4 + 2][nn]); u.w = f2bf(Ts[c4 + 3][nn]);
        *(ushort4*)&Wt[(size_t)(n0 + nn) * D_MODEL + k0 + c4] = u;
    }
}

// ---------------------------------------------------------------------------
// V [bh][2048][64] bf16 -> Vt [bh][64][2048] bf16 (transpose)
// ---------------------------------------------------------------------------
__global__ __launch_bounds__(256)
void transpose_v_kernel(const ushort* __restrict__ V, ushort* __restrict__ Vt)
{
    __shared__ ushort Ts[64][68];
    const int t  = threadIdx.x;
    const int s0 = blockIdx.x * 64;
    const int bh = blockIdx.y;
    const int rr = t >> 4;
    const int c4 = (t & 15) * 4;

#pragma unroll
    for (int i = 0; i < 4; ++i) {
        const int r = rr + i * 16;
        const ushort4 v = *(const ushort4*)&V[((size_t)bh * SEQ + s0 + r) * D_HEAD + c4];
        Ts[r][c4 + 0] = v.x; Ts[r][c4 + 1] = v.y;
        Ts[r][c4 + 2] = v.z; Ts[r][c4 + 3] = v.w;
    }
    __syncthreads();
#pragma unroll
    for (int i = 0; i < 4; ++i) {
        const int dh = rr + i * 16;
        ushort4 u;
        u.x = Ts[c4 + 0][dh]; u.y = Ts[c4 + 1][dh];
        u.z = Ts[c4 + 2][dh]; u.w = Ts[c4 + 3][dh];
        *(ushort4*)&Vt[((size_t)bh * D_HEAD + dh) * SEQ + s0 + c4] = u;
    }
}

// ---------------------------------------------------------------------------
// Merged QKV GEMM: bf16 MFMA, 128x128 tile, BK=64, 4 waves.
// ---------------------------------------------------------------------------
__global__ __launch_bounds__(256)
void gemm_qkv_mfma(const ushort* __restrict__ A, const ushort* __restrict__ Bt,
                   const float* __restrict__ bq, const float* __restrict__ bk,
                   const float* __restrict__ bv, ushort* __restrict__ QKV)
{
    __shared__ ushort As[128 * 64];
    __shared__ ushort Bs[128 * 64];

    const int t    = threadIdx.x;
    const int lane = t & 63;
    const int w    = t >> 6;
    const int wr   = w >> 1;
    const int wc   = w & 1;
    const int l16  = lane & 15;
    const int g    = lane >> 4;
    const int m0   = blockIdx.y * 128;
    const int n0   = blockIdx.x * 128;

    f32x4 acc[4][4];
#pragma unroll
    for (int i = 0; i < 4; ++i)
#pragma unroll
        for (int j = 0; j < 4; ++j) acc[i][j] = f32x4{0.f, 0.f, 0.f, 0.f};

    for (int kt = 0; kt < D_MODEL; kt += 64) {
        __syncthreads();
        const ushort* Ag = A  + (size_t)m0 * D_MODEL + kt;
        const ushort* Bg = Bt + (size_t)n0 * D_MODEL + kt;
#pragma unroll
        for (int it = 0; it < 4; ++it) {
            const int b   = (it * 256 + t) * 16;
            const int row = b >> 7;
            const int src = (b & 127) ^ ((row & 7) << 4);
            const int lof = (it * 256 + (t & ~63)) * 8;
            gload_lds16(Ag + (size_t)row * D_MODEL + (src >> 1), As + lof);
            gload_lds16(Bg + (size_t)row * D_MODEL + (src >> 1), Bs + lof);
        }
        __syncthreads();

#pragma unroll
        for (int kh = 0; kh < 2; ++kh) {
            short8 a[4], bfr[4];
#pragma unroll
            for (int fm = 0; fm < 4; ++fm) {
                const int row  = wr * 64 + fm * 16 + l16;
                const int byte = row * 128 + (((kh << 6) | (g << 4)) ^ ((row & 7) << 4));
                a[fm] = *(const short8*)((const char*)As + byte);
            }
#pragma unroll
            for (int fn = 0; fn < 4; ++fn) {
                const int row  = wc * 64 + fn * 16 + l16;
                const int byte = row * 128 + (((kh << 6) | (g << 4)) ^ ((row & 7) << 4));
                bfr[fn] = *(const short8*)((const char*)Bs + byte);
            }
#pragma unroll
            for (int fm = 0; fm < 4; ++fm)
#pragma unroll
                for (int fn = 0; fn < 4; ++fn)
                    acc[fm][fn] = __builtin_amdgcn_mfma_f32_16x16x32_bf16(a[fm], bfr[fn], acc[fm][fn], 0, 0, 0);
        }
    }

#pragma unroll
    for (int fm = 0; fm < 4; ++fm) {
        const int mb = m0 + wr * 64 + fm * 16 + g * 4;
#pragma unroll
        for (int fn = 0; fn < 4; ++fn) {
            const int n    = n0 + wc * 64 + fn * 16 + l16;
            const int proj = n >> 10;
            const int nn   = n & 1023;
            const float bn = (proj == 0) ? bq[nn] : (proj == 1) ? bk[nn] : bv[nn];
            const float sc = (proj == 0) ? 0.125f : 1.0f;
            ushort* outp = QKV + (size_t)proj * M_TOT * D_MODEL;
#pragma unroll
            for (int r = 0; r < 4; ++r) {
                const float c = (acc[fm][fn][r] + bn) * sc;
                const int m  = mb + r;
                const int bb = m >> 11;
                const int s  = m & (SEQ - 1);
                const int h  = nn >> 6;
                const int dh = nn & 63;
                outp[(((size_t)(bb * N_HEADS + h)) * SEQ + s) * D_HEAD + dh] = f2bf(c);
            }
        }
    }
}

// ---------------------------------------------------------------------------
// Output-projection GEMM (bf16 MFMA, fp32 out): out = AO @ Wot^T + bo
// ---------------------------------------------------------------------------
__global__ __launch_bounds__(256)
void gemm_out_mfma(const ushort* __restrict__ A, const ushort* __restrict__ Bt,
                   const float* __restrict__ bias, float* __restrict__ outp)
{
    __shared__ ushort As[128 * 64];
    __shared__ ushort Bs[128 * 64];

    const int t    = threadIdx.x;
    const int lane = t & 63;
    const int w    = t >> 6;
    const int wr   = w >> 1;
    const int wc   = w & 1;
    const int l16  = lane & 15;
    const int g    = lane >> 4;
    const int m0   = blockIdx.y * 128;
    const int n0   = blockIdx.x * 128;

    f32x4 acc[4][4];
#pragma unroll
    for (int i = 0; i < 4; ++i)
#pragma unroll
        for (int j = 0; j < 4; ++j) acc[i][j] = f32x4{0.f, 0.f, 0.f, 0.f};

    for (int kt = 0; kt < D_MODEL; kt += 64) {
        __syncthreads();
        const ushort* Ag = A  + (size_t)m0 * D_MODEL + kt;
        const ushort* Bg = Bt + (size_t)n0 * D_MODEL + kt;
#pragma unroll
        for (int it = 0; it < 4; ++it) {
            const int b   = (it * 256 + t) * 16;
            const int row = b >> 7;
            const int src = (b & 127) ^ ((row & 7) << 4);
            const int lof = (it * 256 + (t & ~63)) * 8;
            gload_lds16(Ag + (size_t)row * D_MODEL + (src >> 1), As + lof);
            gload_lds16(Bg + (size_t)row * D_MODEL + (src >> 1), Bs + lof);
        }
        __syncthreads();

#pragma unroll
        for (int kh = 0; kh < 2; ++kh) {
            short8 a[4], bfr[4];
#pragma unroll
            for (int fm = 0; fm < 4; ++fm) {
                const int row  = wr * 64 + fm * 16 + l16;
                const int byte = row * 128 + (((kh << 6) | (g << 4)) ^ ((row & 7) << 4));
                a[fm] = *(const short8*)((const char*)As + byte);
            }
#pragma unroll
            for (int fn = 0; fn < 4; ++fn) {
                const int row  = wc * 64 + fn * 16 + l16;
                const int byte = row * 128 + (((kh << 6) | (g << 4)) ^ ((row & 7) << 4));
                bfr[fn] = *(const short8*)((const char*)Bs + byte);
            }
#pragma unroll
            for (int fm = 0; fm < 4; ++fm)
#pragma unroll
                for (int fn = 0; fn < 4; ++fn)
                    acc[fm][fn] = __builtin_amdgcn_mfma_f32_16x16x32_bf16(a[fm], bfr[fn], acc[fm][fn], 0, 0, 0);
        }
    }

#pragma unroll
    for (int fm = 0; fm < 4; ++fm) {
        const int mb = m0 + wr * 64 + fm * 16 + g * 4;
#pragma unroll
        for (int fn = 0; fn < 4; ++fn) {
            const int n  = n0 + wc * 64 + fn * 16 + l16;
            const float bn = bias[n];
#pragma unroll
            for (int r = 0; r < 4; ++r)
                outp[(size_t)(mb + r) * D_MODEL + n] = acc[fm][fn][r] + bn;
        }
    }
}

// ---------------------------------------------------------------------------
// Flash attention v3: swapped-QK^T, block-shared double-buffered LDS K/V.
// Grid (SEQ/128, BH). Block = 4 waves; wave owns 32 q-rows (2x16 sub-tiles).
// Per 64-key tile: stage next K/Vt tile via global_load_lds (XOR-swizzled
// source, linear LDS dest); compute from current buffer (swizzled ds_read).
// One barrier per iteration (drains vmcnt). Defer-max rescale (THR=8).
// ---------------------------------------------------------------------------
__global__ __launch_bounds__(256)
void flash_attn_mfma(const ushort* __restrict__ Q, const ushort* __restrict__ K,
                     const ushort* __restrict__ Vt, ushort* __restrict__ AO)
{
    __shared__ ushort Kl[2][64 * 64];      // [buf] 64 keys x 64 d, swizzled rows
    __shared__ ushort Vl[2][64 * 64];      // [buf] 64 d x 64 keys, swizzled rows
    __shared__ ushort Ps[4][2][16][80];    // [wave][subtile][q][key] stride 80

    const int t    = threadIdx.x;
    const int w    = t >> 6;
    const int lane = t & 63;
    const int l16  = lane & 15;
    const int g    = lane >> 4;
    const int qt   = blockIdx.x;
    const int bh   = blockIdx.y;

    const size_t qkbase = (size_t)bh * SEQ * D_HEAD;
    const ushort* Vg0 = Vt + (size_t)bh * D_HEAD * SEQ;   // rows=d, stride SEQ

    // Q fragments (B operand), two 16-row sub-tiles
    short8 qf[2][2];
#pragma unroll
    for (int tt = 0; tt < 2; ++tt) {
        const int q0 = qt * 128 + w * 32 + tt * 16;
        const ushort* qp = Q + qkbase + (size_t)(q0 + l16) * D_HEAD + g * 8;
        qf[tt][0] = *(const short8*)(qp);
        qf[tt][1] = *(const short8*)(qp + 32);
    }

    f32x4 o[2][4];
    float m_r[2], l_r[2];
#pragma unroll
    for (int tt = 0; tt < 2; ++tt) {
        m_r[tt] = -INFINITY; l_r[tt] = 0.f;
#pragma unroll
        for (int d = 0; d < 4; ++d) o[tt][d] = f32x4{0.f, 0.f, 0.f, 0.f};
    }

    // ---- staging helper (macro-ish lambda): tile kt into buffer b
    auto stage = [&](int ktile, int b) {
        const ushort* Kg = K + qkbase + (size_t)(ktile * 64) * D_HEAD;
        const ushort* Vg = Vg0 + ktile * 64;
#pragma unroll
        for (int it = 0; it < 2; ++it) {
            const int bb  = (it * 256 + t) * 16;
            const int row = bb >> 7;
            const int src = (bb & 127) ^ ((row & 7) << 4);
            const int lof = (it * 256 + (t & ~63)) * 8;
            gload_lds16(Kg + (size_t)row * D_HEAD + (src >> 1), &Kl[b][lof]);
            gload_lds16(Vg + (size_t)row * SEQ + (src >> 1), &Vl[b][lof]);
        }
    };

    stage(0, 0);
    __syncthreads();

    const int NT = SEQ / 64;
    for (int kt = 0; kt < NT; ++kt) {
        const int buf = kt & 1;
        if (kt + 1 < NT) stage(kt + 1, buf ^ 1);

        // ---- K fragments from LDS (shared by both sub-tiles)
        short8 kf[4][2];
#pragma unroll
        for (int nt = 0; nt < 4; ++nt) {
            const int row = nt * 16 + l16;
#pragma unroll
            for (int ks = 0; ks < 2; ++ks) {
                const int byte = row * 128 + (((ks * 64) | (g * 16)) ^ ((row & 7) << 4));
                kf[nt][ks] = *(const short8*)((const char*)&Kl[buf][0] + byte);
            }
        }

        // ---- S^T = K @ Q^T for both sub-tiles
        f32x4 st[2][4];
#pragma unroll
        for (int tt = 0; tt < 2; ++tt)
#pragma unroll
            for (int nt = 0; nt < 4; ++nt) {
                f32x4 a = f32x4{0.f, 0.f, 0.f, 0.f};
                a = __builtin_amdgcn_mfma_f32_16x16x32_bf16(kf[nt][0], qf[tt][0], a, 0, 0, 0);
                a = __builtin_amdgcn_mfma_f32_16x16x32_bf16(kf[nt][1], qf[tt][1], a, 0, 0, 0);
                st[tt][nt] = a;
            }

        // ---- softmax per sub-tile (row q = l16 local; defer-max THR=8)
#pragma unroll
        for (int tt = 0; tt < 2; ++tt) {
            float pmax = st[tt][0][0];
#pragma unroll
            for (int nt = 0; nt < 4; ++nt)
#pragma unroll
                for (int r = 0; r < 4; ++r) pmax = fmaxf(pmax, st[tt][nt][r]);
            pmax = fmaxf(pmax, __shfl_xor(pmax, 16, 64));
            pmax = fmaxf(pmax, __shfl_xor(pmax, 32, 64));

            if (__any(pmax - m_r[tt] > 8.f)) {
                const float mnew  = fmaxf(m_r[tt], pmax);
                const float alpha = __expf(m_r[tt] - mnew);
                m_r[tt] = mnew;
                l_r[tt] *= alpha;
                float ar[4];
#pragma unroll
                for (int r = 0; r < 4; ++r) ar[r] = __shfl(alpha, g * 4 + r, 64);
#pragma unroll
                for (int dt = 0; dt < 4; ++dt)
#pragma unroll
                    for (int r = 0; r < 4; ++r) o[tt][dt][r] *= ar[r];
            }

            float rs = 0.f;
#pragma unroll
            for (int nt = 0; nt < 4; ++nt) {
                ushort4 pk;
#pragma unroll
                for (int r = 0; r < 4; ++r) {
                    const float p = __expf(st[tt][nt][r] - m_r[tt]);
                    rs += p;
                    ((ushort*)&pk)[r] = f2bf(p);
                }
                *(ushort4*)&Ps[w][tt][l16][nt * 16 + g * 4] = pk;
            }
            rs += __shfl_xor(rs, 16, 64);
            rs += __shfl_xor(rs, 32, 64);
            l_r[tt] += rs;
        }

        // ---- V fragments from LDS (shared by both sub-tiles)
        short8 vf[4][2];
#pragma unroll
        for (int dt = 0; dt < 4; ++dt) {
            const int row = dt * 16 + l16;
#pragma unroll
            for (int ks = 0; ks < 2; ++ks) {
                const int byte = row * 128 + (((ks * 64) | (g * 16)) ^ ((row & 7) << 4));
                vf[dt][ks] = *(const short8*)((const char*)&Vl[buf][0] + byte);
            }
        }

        // ---- O += P @ V for both sub-tiles
#pragma unroll
        for (int tt = 0; tt < 2; ++tt)
#pragma unroll
            for (int ks = 0; ks < 2; ++ks) {
                const short8 pf = *(const short8*)&Ps[w][tt][l16][ks * 32 + g * 8];
#pragma unroll
                for (int dt = 0; dt < 4; ++dt)
                    o[tt][dt] = __builtin_amdgcn_mfma_f32_16x16x32_bf16(pf, vf[dt][ks], o[tt][dt], 0, 0, 0);
            }

        __syncthreads();   // staging drained (vmcnt0); all reads of buf done
    }

    // ---- epilogue: AO[b][s][h*64+d] bf16
    const int b = bh >> 4;
    const int h = bh & 15;
#pragma unroll
    for (int tt = 0; tt < 2; ++tt) {
        const int q0 = qt * 128 + w * 32 + tt * 16;
        float lr_row[4];
#pragma unroll
        for (int r = 0; r < 4; ++r) lr_row[r] = __shfl(l_r[tt], g * 4 + r, 64);
#pragma unroll
        for (int r = 0; r < 4; ++r) {
            const float inv = 1.f / lr_row[r];
            const size_t row = (size_t)b * SEQ + q0 + g * 4 + r;
#pragma unroll
            for (int dt = 0; dt < 4; ++dt)
                AO[row * D_MODEL + h * D_HEAD + dt * 16 + l16] = f2bf(o[tt][dt][r] * inv);
        }
    }
}

// ---------------------------------------------------------------------------
extern "C" void kernel_launch(void* const* d_in, const int* in_sizes, int n_in,
                              void* d_out, int out_size, void* d_ws, size_t ws_size,
                              hipStream_t stream)
{
    const float* x  = (const float*)d_in[0];
    const float* Wq = (const float*)d_in[1];
    const float* bq = (const float*)d_in[2];
    const float* Wk = (const float*)d_in[3];
    const float* bk = (const float*)d_in[4];
    const float* Wv = (const float*)d_in[5];
    const float* bv = (const float*)d_in[6];
    const float* Wo = (const float*)d_in[7];
    const float* bo = (const float*)d_in[8];
    float* out = (float*)d_out;

    const size_t NELT = (size_t)M_TOT * D_MODEL;     // 4M
    const size_t WELT = (size_t)D_MODEL * D_MODEL;   // 1M
    ushort* xb  = (ushort*)d_ws;        // [4096][1024] bf16; reused as Vt later
    ushort* Wqt = xb + NELT;            // Wqt/Wkt/Wvt/Wot contiguous [N][K]
    ushort* Wot = Wqt + 3 * WELT;
    ushort* Qb  = xb + 2 * NELT;        // Qb/Kb/Vb contiguous head layout
    ushort* Vb  = xb + 4 * NELT;
    ushort* Vtb = xb;                   // aliases xb (dead after QKV GEMM)
    ushort* AOb = Vb;                   // aliases Vb (dead after V transpose)

    f32_to_bf16_kernel<<<dim3((M_TOT * D_MODEL / 4 + 255) / 256), 256, 0, stream>>>(x, xb, M_TOT * D_MODEL / 4);
    transpose_w4_kernel<<<dim3(D_MODEL / 64, D_MODEL / 64, 4), 256, 0, stream>>>(Wq, Wk, Wv, Wo, Wqt);
    gemm_qkv_mfma<<<dim3(3 * D_MODEL / 128, M_TOT / 128), 256, 0, stream>>>(xb, Wqt, bq, bk, bv, Qb);
    transpose_v_kernel<<<dim3(SEQ / 64, BATCH * N_HEADS), 256, 0, stream>>>(Vb, Vtb);
    flash_attn_mfma<<<dim3(SEQ / 128, BATCH * N_HEADS), 256, 0, stream>>>(Qb, Qb + NELT, Vtb, AOb);
    gemm_out_mfma<<<dim3(D_MODEL / 128, M_TOT / 128), 256, 0, stream>>>(AOb, Wot, bo, out);
}